// Round 11
// baseline (576.455 us; speedup 1.0000x reference)
//
#include <hip/hip_runtime.h>

#define EDIM 1024
#define LNUM 24
#define FDIM 4096
#define NB 256   // persistent blocks, 1 per CU
#define NT 512   // 8 waves per block

__device__ __forceinline__ float wave_sum(float v) {
#pragma unroll
    for (int off = 32; off > 0; off >>= 1) v += __shfl_xor(v, off, 64);
    return v;
}
__device__ __forceinline__ float2 wave_sum2(float a, float b) {
#pragma unroll
    for (int off = 32; off > 0; off >>= 1) {
        a += __shfl_xor(a, off, 64);
        b += __shfl_xor(b, off, 64);
    }
    return make_float2(a, b);
}

// Coherent (MALL-visible) accessors for cross-block data.
__device__ __forceinline__ float2 cload2(const float* p) {
    double d = __hip_atomic_load((const double*)p, __ATOMIC_RELAXED,
                                 __HIP_MEMORY_SCOPE_AGENT);
    float2 r;
    __builtin_memcpy(&r, &d, 8);
    return r;
}
__device__ __forceinline__ float4 cload4(const float* p) {
    const float2 a = cload2(p), b = cload2(p + 2);
    return make_float4(a.x, a.y, b.x, b.y);
}
__device__ __forceinline__ float cload1(const float* p) {
    return __hip_atomic_load(p, __ATOMIC_RELAXED, __HIP_MEMORY_SCOPE_AGENT);
}
__device__ __forceinline__ void cstore1(float* p, float v) {
    __hip_atomic_store(p, v, __ATOMIC_RELAXED, __HIP_MEMORY_SCOPE_AGENT);
}

#define FENCE()                            \
    do {                                   \
        asm volatile("" ::: "memory");     \
        __builtin_amdgcn_sched_barrier(0); \
    } while (0)

// Intra-block barrier that does NOT drain vmcnt.
__device__ __forceinline__ void lbar() {
    asm volatile("s_waitcnt lgkmcnt(0)" ::: "memory");
    __builtin_amdgcn_sched_barrier(0);
    __builtin_amdgcn_s_barrier();
    asm volatile("" ::: "memory");
    __builtin_amdgcn_sched_barrier(0);
}

// Device-wide barrier, counted vmcnt. Arrival: 8 group lines x 32 atomics.
// Each group-last polls the 8 arrival lines, then writes ONE release word for
// its own group (8 stores total); members poll their group's release word
// (31 pollers/line). Removes round-10's 256-store flag fanout.
template <int P>
__device__ __forceinline__ void gbar(unsigned* grp, unsigned* rel, unsigned& bi) {
    asm volatile("s_waitcnt vmcnt(%0) lgkmcnt(0)" ::"i"(P) : "memory");
    __builtin_amdgcn_sched_barrier(0);
    __builtin_amdgcn_s_barrier();  // all waves: this block's stores drained
    const unsigned bi1 = bi + 1u;
    if (threadIdx.x == 0) {
        const int g = blockIdx.x & 7;
        const unsigned o = __hip_atomic_fetch_add(&grp[g << 4], 1u, __ATOMIC_RELAXED,
                                                  __HIP_MEMORY_SCOPE_AGENT);
        if ((o & 31u) == 31u) {  // group-last this epoch
            const unsigned tgt = 32u * bi1;
            int guard = 0;
            for (;;) {
                unsigned mn = 0xffffffffu;
#pragma unroll
                for (int i = 0; i < 8; ++i) {
                    const unsigned v = __hip_atomic_load(
                        &grp[i << 4], __ATOMIC_RELAXED, __HIP_MEMORY_SCOPE_AGENT);
                    mn = v < mn ? v : mn;
                }
                if (mn >= tgt) break;
                if (++guard > (1 << 20)) break;  // fail-fast bailout
            }
            __hip_atomic_store(&rel[g << 4], bi1, __ATOMIC_RELAXED,
                               __HIP_MEMORY_SCOPE_AGENT);
        } else {
            int guard = 0;
            while (__hip_atomic_load(&rel[(blockIdx.x & 7) << 4], __ATOMIC_RELAXED,
                                     __HIP_MEMORY_SCOPE_AGENT) < bi1) {
                __builtin_amdgcn_s_sleep(1);
                if (++guard > (1 << 22)) break;
            }
        }
    }
    __builtin_amdgcn_s_barrier();
    asm volatile("" ::: "memory");
    __builtin_amdgcn_sched_barrier(0);
    ++bi;
}

__device__ __forceinline__ float dotp4(const float4& a, const float4& b) {
    return a.x * b.x + a.y * b.y + a.z * b.z + a.w * b.w;
}

// Per-quarter op-build + dot accumulate for phase A. QI compile-time.
#define PHASE_A_Q(XQ, PA, QI)                                              \
    {                                                                      \
        const float4 lw = LW1[lane + QI * 64];                             \
        const float4 lb = LB1[lane + QI * 64];                             \
        const float4 av = SAv[lane + QI * 64];                             \
        const float4 mx = MXv[lane + QI * 64];                             \
        float4 xn, op;                                                     \
        xn.x = (XQ.x - mu) * inv * lw.x + lb.x;                            \
        xn.y = (XQ.y - mu) * inv * lw.y + lb.y;                            \
        xn.z = (XQ.z - mu) * inv * lw.z + lb.z;                            \
        xn.w = (XQ.w - mu) * inv * lw.w + lb.w;                            \
        op.x = xn.x + mx.x * av.x; op.y = xn.y + mx.y * av.y;              \
        op.z = xn.z + mx.z * av.z; op.w = xn.w + mx.w * av.w;              \
        acc += dotp4(PA, op);                                              \
        if ((QI >> 1) == rh) {                                             \
            const float4 mr4 = MRv[lane + QI * 64];                        \
            op.x = xn.x + mr4.x * av.x; op.y = xn.y + mr4.y * av.y;        \
            op.z = xn.z + mr4.z * av.z; op.w = xn.w + mr4.w * av.w;        \
            accR += dotp4(((QI & 1) ? rA1 : rA0), op);                     \
        }                                                                  \
    }

#define PHASE_C_Q(SQ, PC1, PC2, QI)                                        \
    {                                                                      \
        const float4 lw = LW2[lane + QI * 64];                             \
        const float4 lb = LB2[lane + QI * 64];                             \
        const float4 sd4 = SDv[lane + QI * 64];                            \
        const float4 mf = MKFv[lane + QI * 64];                            \
        float4 x2, op;                                                     \
        x2.x = (SQ.x - mu) * inv * lw.x + lb.x;                            \
        x2.y = (SQ.y - mu) * inv * lw.y + lb.y;                            \
        x2.z = (SQ.z - mu) * inv * lw.z + lb.z;                            \
        x2.w = (SQ.w - mu) * inv * lw.w + lb.w;                            \
        op.x = x2.x + mf.x * sd4.x; op.y = x2.y + mf.y * sd4.y;            \
        op.z = x2.z + mf.z * sd4.z; op.w = x2.w + mf.w * sd4.w;            \
        accF1 += dotp4(PC1, op);                                           \
        accF2 += dotp4(PC2, op);                                           \
        if ((QI >> 1) == rh) {                                             \
            const float4 mr4 = MRFv[lane + QI * 64];                       \
            op.x = x2.x + mr4.x * sd4.x; op.y = x2.y + mr4.y * sd4.y;      \
            op.z = x2.z + mr4.z * sd4.z; op.w = x2.w + mr4.w * sd4.w;      \
            accRF += dotp4(((QI & 1) ? rC1 : rC0), op);                    \
        }                                                                  \
    }

__global__ __launch_bounds__(NT, 2) void rwkv_persistent(
    const float* __restrict__ x_in, const float* __restrict__ state,
    const float* __restrict__ ln1w, const float* __restrict__ ln1b,
    const float* __restrict__ ln2w, const float* __restrict__ ln2b,
    const float* __restrict__ td, const float* __restrict__ tf,
    const float* __restrict__ key, const float* __restrict__ ow,
    const float* __restrict__ mixk, const float* __restrict__ mixv,
    const float* __restrict__ mixr, const float* __restrict__ mixkf,
    const float* __restrict__ mixrf, const float* __restrict__ kffn,
    const float* __restrict__ rffn, const float* __restrict__ vffn,
    float* __restrict__ out, float* __restrict__ ws, unsigned* __restrict__ grp,
    unsigned* __restrict__ rel) {
    __shared__ float red[32];
    // red[0..15]: dot partials; red[16..23]: half-dot partials;
    // red[24..27]: x[4b..4b+4) handoff (A->B); red[28..31]: sx handoff (C->D)

    float* kbuf = ws;          // [1024] exp(k)         (coherent)
    float* vbuf = ws + 1024;   // [1024] v
    float* rbuf = ws + 2048;   // [1024] rhat=exp(r)+1  (combined in A tail)
    float* sxbuf = ws + 3072;  // [1024] sx             (combined in B tail)
    float* kfbuf = ws + 4096;  // [4096] relu^2(kf)
    float* xnext = ws + 8192;  // [1024] next-layer x   (combined in D tail)

    float* sa_out = out + EDIM;
    float* sb_out = sa_out + LNUM * EDIM;
    float* sc_out = sb_out + LNUM * EDIM;
    float* sd_out = sc_out + LNUM * EDIM;

    const float* stB = state + 1 * LNUM * EDIM;
    const float* stC = state + 2 * LNUM * EDIM;

    const int t = threadIdx.x;
    const int b = blockIdx.x;
    const int w = t >> 6;
    const int lane = t & 63;
    const int gw = (b << 3) + w;           // 0..2047
    const int mat = gw >> 10;              // 0 -> k row, 1 -> v row
    const int rrow = (b << 2) + (w >> 1);  // r / ow / rfw row; half rh
    const int rh = w & 1;
    const int drow = (b << 2) + (w >> 2);  // vfw rows; chunk dch
    const int dch = w & 3;
    const int eb = b << 2;   // block's owned 4-element slice base
    const int e0 = lane << 2;  // lane's first element within a 256-span
    unsigned bi = 0;

    float4 pA0, pA1, pA2, pA3, rA0, rA1;
    float4 pB0, pB1;
    float4 pC10, pC11, pC12, pC13, pC20, pC21, pC22, pC23, rC0, rC1;
    float4 pD0, pD1, pD2, pD3, pD4, pD5, pD6, pD7;

    // Prologue: layer-0 phase-A weights (normal loads).
    {
        const float4* qA = (const float4*)(key + ((size_t)gw << 10));
        pA0 = qA[lane]; pA1 = qA[lane + 64]; pA2 = qA[lane + 128]; pA3 = qA[lane + 192];
        const float4* qR =
            (const float4*)(key + ((size_t)(2048 + rrow) << 10) + (rh << 9));
        rA0 = qR[lane]; rA1 = qR[lane + 64];
    }

    for (int l = 0; l < LNUM; ++l) {
        const float* owl = ow + (size_t)l * EDIM * EDIM;
        const float* kfl = kffn + (size_t)l * FDIM * EDIM;
        const float* rfl = rffn + (size_t)l * EDIM * EDIM;
        const float* vfl = vffn + (size_t)l * EDIM * FDIM;
        const int le = l * EDIM;
        float gt = 0.0f;  // sigmoid gate, lives C-tail -> D-tail in register

        // ========== Phase A: per-wave LN1 + k/v/r dots, register-direct ==========
        {
            float4 xq0, xq1, xq2, xq3;
            if (l == 0) {
                const float4* xp = (const float4*)x_in;
                xq0 = xp[lane]; xq1 = xp[lane + 64];
                xq2 = xp[lane + 128]; xq3 = xp[lane + 192];
            } else {
                xq0 = cload4(xnext + e0);
                xq1 = cload4(xnext + 256 + e0);
                xq2 = cload4(xnext + 512 + e0);
                xq3 = cload4(xnext + 768 + e0);
            }
            // full-vector stats from one wave (lanes cover all 1024 elements)
            const float s = (xq0.x + xq0.y + xq0.z + xq0.w) +
                            (xq1.x + xq1.y + xq1.z + xq1.w) +
                            (xq2.x + xq2.y + xq2.z + xq2.w) +
                            (xq3.x + xq3.y + xq3.z + xq3.w);
            const float s2 = dotp4(xq0, xq0) + dotp4(xq1, xq1) +
                             dotp4(xq2, xq2) + dotp4(xq3, xq3);
            const float2 ss = wave_sum2(s, s2);
            const float mu = ss.x * (1.0f / 1024.0f);
            const float inv = rsqrtf(ss.y * (1.0f / 1024.0f) - mu * mu + 1e-5f);

            const float4* LW1 = (const float4*)(ln1w + le);
            const float4* LB1 = (const float4*)(ln1b + le);
            const float4* SAv = (const float4*)(state + le);
            const float4* MXv = (const float4*)((mat ? mixv : mixk) + le);
            const float4* MRv = (const float4*)(mixr + le);
            float acc = 0.0f, accR = 0.0f;
            PHASE_A_Q(xq0, pA0, 0)
            PHASE_A_Q(xq1, pA1, 1)
            PHASE_A_Q(xq2, pA2, 2)
            PHASE_A_Q(xq3, pA3, 3)
            const float2 dv = wave_sum2(acc, accR);
            if (lane == 0) {
                if (mat == 0) cstore1(kbuf + gw, expf(dv.x));
                else          cstore1(vbuf + gw - 1024, dv.x);
                red[16 + w] = dv.y;
            }
            // sa output + x handoff for B tail (wave 0, one lane)
            if (w == 0) {
                const int q = b >> 6;  // uniform per block
                const float4 xs = q == 0 ? xq0 : q == 1 ? xq1 : q == 2 ? xq2 : xq3;
                if (lane == (b & 63)) {
                    const float4 lw = *(const float4*)(ln1w + le + eb);
                    const float4 lb = *(const float4*)(ln1b + le + eb);
                    float4 xn;
                    xn.x = (xs.x - mu) * inv * lw.x + lb.x;
                    xn.y = (xs.y - mu) * inv * lw.y + lb.y;
                    xn.z = (xs.z - mu) * inv * lw.z + lb.z;
                    xn.w = (xs.w - mu) * inv * lw.w + lb.w;
                    *(float4*)(sa_out + le + eb) = xn;
                    red[24] = xs.x; red[25] = xs.y; red[26] = xs.z; red[27] = xs.w;
                }
            }
            lbar();
            if (t < 4)
                cstore1(rbuf + eb + t, expf(red[16 + 2 * t] + red[17 + 2 * t]) + 1.0f);
        }
        FENCE();
        {   // window A->B: pB (ow half-row) + pC1 (kfw row gw) = 6 loads
            const float4* qB = (const float4*)(owl + ((size_t)rrow << 10) + (rh << 9));
            pB0 = qB[lane]; pB1 = qB[lane + 64];
            const float4* q1 = (const float4*)(kfl + ((size_t)gw << 10));
            pC10 = q1[lane]; pC11 = q1[lane + 64]; pC12 = q1[lane + 128]; pC13 = q1[lane + 192];
        }
        gbar<6>(grp, rel, bi);

        // ========== Phase B: WKV elementwise (register) + ow half-dot ==========
        {
            float kj = 0.0f, vj = 0.0f;
            if (t < 4) { kj = cload1(kbuf + eb + t); vj = cload1(vbuf + eb + t); }
            const int gp0 = (rh << 9) + e0;
            const int gp1 = gp0 + 256;
            const float4 k0 = cload4(kbuf + gp0), k1 = cload4(kbuf + gp1);
            const float4 v0 = cload4(vbuf + gp0), v1 = cload4(vbuf + gp1);
            const float4 r0 = cload4(rbuf + gp0), r1 = cload4(rbuf + gp1);
            const float4 tf0 = *(const float4*)(tf + le + gp0);
            const float4 tf1 = *(const float4*)(tf + le + gp1);
            const float4 sb0 = *(const float4*)(stB + le + gp0);
            const float4 sb1 = *(const float4*)(stB + le + gp1);
            const float4 sc0 = *(const float4*)(stC + le + gp0);
            const float4 sc1 = *(const float4*)(stC + le + gp1);
            float4 g0, g1;
            g0.x = (sb0.x + tf0.x * k0.x * v0.x) / (sc0.x * r0.x + tf0.x * k0.x * r0.x);
            g0.y = (sb0.y + tf0.y * k0.y * v0.y) / (sc0.y * r0.y + tf0.y * k0.y * r0.y);
            g0.z = (sb0.z + tf0.z * k0.z * v0.z) / (sc0.z * r0.z + tf0.z * k0.z * r0.z);
            g0.w = (sb0.w + tf0.w * k0.w * v0.w) / (sc0.w * r0.w + tf0.w * k0.w * r0.w);
            g1.x = (sb1.x + tf1.x * k1.x * v1.x) / (sc1.x * r1.x + tf1.x * k1.x * r1.x);
            g1.y = (sb1.y + tf1.y * k1.y * v1.y) / (sc1.y * r1.y + tf1.y * k1.y * r1.y);
            g1.z = (sb1.z + tf1.z * k1.z * v1.z) / (sc1.z * r1.z + tf1.z * k1.z * r1.z);
            g1.w = (sb1.w + tf1.w * k1.w * v1.w) / (sc1.w * r1.w + tf1.w * k1.w * r1.w);
            const float pd = wave_sum(dotp4(pB0, g0) + dotp4(pB1, g1));
            if (lane == 0) red[w] = pd;
            if (t < 4) {  // state outputs for own slice
                const int j = le + eb + t;
                const float tdj = td[j];
                sb_out[j] = stB[j] * tdj + kj * vj;
                sc_out[j] = stC[j] * tdj + kj;
            }
            lbar();
            if (t < 4)
                cstore1(sxbuf + eb + t, red[24 + t] + red[2 * t] + red[2 * t + 1]);
        }
        FENCE();
        {   // window B->C: pC2 (kfw row gw+2048) + rC (rfw half-row) = 6 loads
            const float4* q2 = (const float4*)(kfl + ((size_t)(gw + 2048) << 10));
            pC20 = q2[lane]; pC21 = q2[lane + 64]; pC22 = q2[lane + 128]; pC23 = q2[lane + 192];
            const float4* qR = (const float4*)(rfl + ((size_t)rrow << 10) + (rh << 9));
            rC0 = qR[lane]; rC1 = qR[lane + 64];
        }
        gbar<6>(grp, rel, bi);

        // ========== Phase C: per-wave LN2 + kf/rf dots, register-direct ==========
        {
            const float4 sq0 = cload4(sxbuf + e0);
            const float4 sq1 = cload4(sxbuf + 256 + e0);
            const float4 sq2 = cload4(sxbuf + 512 + e0);
            const float4 sq3 = cload4(sxbuf + 768 + e0);
            const float s = (sq0.x + sq0.y + sq0.z + sq0.w) +
                            (sq1.x + sq1.y + sq1.z + sq1.w) +
                            (sq2.x + sq2.y + sq2.z + sq2.w) +
                            (sq3.x + sq3.y + sq3.z + sq3.w);
            const float s2 = dotp4(sq0, sq0) + dotp4(sq1, sq1) +
                             dotp4(sq2, sq2) + dotp4(sq3, sq3);
            const float2 ss = wave_sum2(s, s2);
            const float mu = ss.x * (1.0f / 1024.0f);
            const float inv = rsqrtf(ss.y * (1.0f / 1024.0f) - mu * mu + 1e-5f);

            const float4* LW2 = (const float4*)(ln2w + le);
            const float4* LB2 = (const float4*)(ln2b + le);
            const float4* SDv = (const float4*)(state + 3 * LNUM * EDIM + le);
            const float4* MKFv = (const float4*)(mixkf + le);
            const float4* MRFv = (const float4*)(mixrf + le);
            float accF1 = 0.0f, accF2 = 0.0f, accRF = 0.0f;
            PHASE_C_Q(sq0, pC10, pC20, 0)
            PHASE_C_Q(sq1, pC11, pC21, 1)
            PHASE_C_Q(sq2, pC12, pC22, 2)
            PHASE_C_Q(sq3, pC13, pC23, 3)
            const float2 df = wave_sum2(accF1, accF2);
            const float dr = wave_sum(accRF);
            if (lane == 0) {
                float r1 = fmaxf(df.x, 0.0f);
                float r2 = fmaxf(df.y, 0.0f);
                cstore1(kfbuf + gw, r1 * r1);
                cstore1(kfbuf + gw + 2048, r2 * r2);
                red[16 + w] = dr;
            }
            // sd output + sx handoff for D tail (wave 0, one lane)
            if (w == 0) {
                const int q = b >> 6;
                const float4 xs = q == 0 ? sq0 : q == 1 ? sq1 : q == 2 ? sq2 : sq3;
                if (lane == (b & 63)) {
                    const float4 lw = *(const float4*)(ln2w + le + eb);
                    const float4 lb = *(const float4*)(ln2b + le + eb);
                    float4 x2;
                    x2.x = (xs.x - mu) * inv * lw.x + lb.x;
                    x2.y = (xs.y - mu) * inv * lw.y + lb.y;
                    x2.z = (xs.z - mu) * inv * lw.z + lb.z;
                    x2.w = (xs.w - mu) * inv * lw.w + lb.w;
                    *(float4*)(sd_out + le + eb) = x2;
                    red[28] = xs.x; red[29] = xs.y; red[30] = xs.z; red[31] = xs.w;
                }
            }
            lbar();
            if (t < 4)
                gt = 1.0f / (1.0f + expf(red[16 + 2 * t] + red[17 + 2 * t]));
        }
        FENCE();
        {   // window C->D: both vfw chunk-units = 8 loads
            const float4* q1 = (const float4*)(vfl + ((size_t)drow << 12) + (dch << 10));
            pD0 = q1[lane]; pD1 = q1[lane + 64]; pD2 = q1[lane + 128]; pD3 = q1[lane + 192];
            const float4* q2 =
                (const float4*)(vfl + ((size_t)(drow + 2) << 12) + (dch << 10));
            pD4 = q2[lane]; pD5 = q2[lane + 64]; pD6 = q2[lane + 128]; pD7 = q2[lane + 192];
        }
        gbar<8>(grp, rel, bi);

        // ========== Phase D: vfw dots, register-direct; combine + gate in tail ==========
        {
            const int kp = dch << 10;
            const float4 o0 = cload4(kfbuf + kp + e0);
            const float4 o1 = cload4(kfbuf + kp + 256 + e0);
            const float4 o2 = cload4(kfbuf + kp + 512 + e0);
            const float4 o3 = cload4(kfbuf + kp + 768 + e0);
            const float2 dd = wave_sum2(
                dotp4(pD0, o0) + dotp4(pD1, o1) + dotp4(pD2, o2) + dotp4(pD3, o3),
                dotp4(pD4, o0) + dotp4(pD5, o1) + dotp4(pD6, o2) + dotp4(pD7, o3));
            if (lane == 0) { red[w] = dd.x; red[8 + w] = dd.y; }
            lbar();
            if (t < 4) {
                const float ffn =
                    red[4 * t] + red[4 * t + 1] + red[4 * t + 2] + red[4 * t + 3];
                const float val = red[28 + t] + ffn * gt;
                if (l == LNUM - 1) out[eb + t] = val;  // final output
                else cstore1(xnext + eb + t, val);
            }
        }
        if (l < LNUM - 1) {
            FENCE();
            {   // window D->A': next layer's phase-A weights = 6 loads
                const float* keyn = key + (size_t)(l + 1) * 3 * EDIM * EDIM;
                const float4* qA = (const float4*)(keyn + ((size_t)gw << 10));
                pA0 = qA[lane]; pA1 = qA[lane + 64]; pA2 = qA[lane + 128]; pA3 = qA[lane + 192];
                const float4* qR =
                    (const float4*)(keyn + ((size_t)(2048 + rrow) << 10) + (rh << 9));
                rA0 = qR[lane]; rA1 = qR[lane + 64];
            }
            gbar<6>(grp, rel, bi);
        }
    }
}

extern "C" void kernel_launch(void* const* d_in, const int* in_sizes, int n_in,
                              void* d_out, int out_size, void* d_ws, size_t ws_size,
                              hipStream_t stream) {
    const float* x_in = (const float*)d_in[0];
    const float* state = (const float*)d_in[1];
    const float* ln1w = (const float*)d_in[2];
    const float* ln1b = (const float*)d_in[3];
    const float* ln2w = (const float*)d_in[4];
    const float* ln2b = (const float*)d_in[5];
    const float* td = (const float*)d_in[6];
    const float* tf = (const float*)d_in[7];
    const float* key = (const float*)d_in[8];
    const float* ow = (const float*)d_in[9];
    const float* mixk = (const float*)d_in[10];
    const float* mixv = (const float*)d_in[11];
    const float* mixr = (const float*)d_in[12];
    const float* mixkf = (const float*)d_in[13];
    const float* mixrf = (const float*)d_in[14];
    const float* kffn = (const float*)d_in[15];
    const float* rffn = (const float*)d_in[16];
    const float* vffn = (const float*)d_in[17];

    float* out = (float*)d_out;
    float* ws = (float*)d_ws;

    // Vector region: 9216 floats = 36 KB. Barrier state at 48 KB:
    // 8 arrival lines (64 B each) + 8 release lines.
    unsigned* bar = (unsigned*)((char*)d_ws + 48 * 1024);
    unsigned* grp = bar;         // grp[g<<4], g=0..7
    unsigned* rel = bar + 256;   // rel[g<<4], g=0..7 (+1 KB)

    hipMemsetAsync(bar, 0, 2048, stream);  // deterministic per replay
    rwkv_persistent<<<NB, NT, 0, stream>>>(x_in, state, ln1w, ln1b, ln2w, ln2b, td, tf,
                                           key, ow, mixk, mixv, mixr, mixkf, mixrf,
                                           kffn, rffn, vffn, out, ws, grp, rel);
}

// Round 12
// 570.748 us; speedup vs baseline: 1.0100x; 1.0100x over previous
//
#include <hip/hip_runtime.h>

#define EDIM 1024
#define LNUM 24
#define FDIM 4096
#define NB 256   // persistent blocks, 1 per CU
#define NT 512   // 8 waves per block

__device__ __forceinline__ float wave_sum(float v) {
#pragma unroll
    for (int off = 32; off > 0; off >>= 1) v += __shfl_xor(v, off, 64);
    return v;
}
__device__ __forceinline__ float2 wave_sum2(float a, float b) {
#pragma unroll
    for (int off = 32; off > 0; off >>= 1) {
        a += __shfl_xor(a, off, 64);
        b += __shfl_xor(b, off, 64);
    }
    return make_float2(a, b);
}

// Coherent (MALL-visible) accessors for cross-block data.
__device__ __forceinline__ float2 cload2(const float* p) {
    double d = __hip_atomic_load((const double*)p, __ATOMIC_RELAXED,
                                 __HIP_MEMORY_SCOPE_AGENT);
    float2 r;
    __builtin_memcpy(&r, &d, 8);
    return r;
}
__device__ __forceinline__ float4 cload4(const float* p) {
    const float2 a = cload2(p), b = cload2(p + 2);
    return make_float4(a.x, a.y, b.x, b.y);
}
__device__ __forceinline__ float cload1(const float* p) {
    return __hip_atomic_load(p, __ATOMIC_RELAXED, __HIP_MEMORY_SCOPE_AGENT);
}
__device__ __forceinline__ void cstore1(float* p, float v) {
    __hip_atomic_store(p, v, __ATOMIC_RELAXED, __HIP_MEMORY_SCOPE_AGENT);
}

#define FENCE()                            \
    do {                                   \
        asm volatile("" ::: "memory");     \
        __builtin_amdgcn_sched_barrier(0); \
    } while (0)

// Intra-block barrier that does NOT drain vmcnt.
__device__ __forceinline__ void lbar() {
    asm volatile("s_waitcnt lgkmcnt(0)" ::: "memory");
    __builtin_amdgcn_sched_barrier(0);
    __builtin_amdgcn_s_barrier();
    asm volatile("" ::: "memory");
    __builtin_amdgcn_sched_barrier(0);
}

// Device-wide barrier, counted vmcnt. Arrival: 8 group lines x 32 atomics.
// Each group-last polls the 8 arrival lines, then writes ONE release word for
// its own group (8 stores total); members poll their group's release word
// (31 pollers/line). Removes round-10's 256-store flag fanout.
template <int P>
__device__ __forceinline__ void gbar(unsigned* grp, unsigned* rel, unsigned& bi) {
    asm volatile("s_waitcnt vmcnt(%0) lgkmcnt(0)" ::"i"(P) : "memory");
    __builtin_amdgcn_sched_barrier(0);
    __builtin_amdgcn_s_barrier();  // all waves: this block's stores drained
    const unsigned bi1 = bi + 1u;
    if (threadIdx.x == 0) {
        const int g = blockIdx.x & 7;
        const unsigned o = __hip_atomic_fetch_add(&grp[g << 4], 1u, __ATOMIC_RELAXED,
                                                  __HIP_MEMORY_SCOPE_AGENT);
        if ((o & 31u) == 31u) {  // group-last this epoch
            const unsigned tgt = 32u * bi1;
            int guard = 0;
            for (;;) {
                unsigned mn = 0xffffffffu;
#pragma unroll
                for (int i = 0; i < 8; ++i) {
                    const unsigned v = __hip_atomic_load(
                        &grp[i << 4], __ATOMIC_RELAXED, __HIP_MEMORY_SCOPE_AGENT);
                    mn = v < mn ? v : mn;
                }
                if (mn >= tgt) break;
                if (++guard > (1 << 20)) break;  // fail-fast bailout
            }
            __hip_atomic_store(&rel[g << 4], bi1, __ATOMIC_RELAXED,
                               __HIP_MEMORY_SCOPE_AGENT);
        } else {
            int guard = 0;
            while (__hip_atomic_load(&rel[(blockIdx.x & 7) << 4], __ATOMIC_RELAXED,
                                     __HIP_MEMORY_SCOPE_AGENT) < bi1) {
                __builtin_amdgcn_s_sleep(1);
                if (++guard > (1 << 22)) break;
            }
        }
    }
    __builtin_amdgcn_s_barrier();
    asm volatile("" ::: "memory");
    __builtin_amdgcn_sched_barrier(0);
    ++bi;
}

__device__ __forceinline__ float dotp4(const float4& a, const float4& b) {
    return a.x * b.x + a.y * b.y + a.z * b.z + a.w * b.w;
}

// Per-quarter op-build + dot accumulate for phase A. QI compile-time.
#define PHASE_A_Q(XQ, PA, QI)                                              \
    {                                                                      \
        const float4 lw = LW1[lane + QI * 64];                             \
        const float4 lb = LB1[lane + QI * 64];                             \
        const float4 av = SAv[lane + QI * 64];                             \
        const float4 mx = MXv[lane + QI * 64];                             \
        float4 xn, op;                                                     \
        xn.x = (XQ.x - mu) * inv * lw.x + lb.x;                            \
        xn.y = (XQ.y - mu) * inv * lw.y + lb.y;                            \
        xn.z = (XQ.z - mu) * inv * lw.z + lb.z;                            \
        xn.w = (XQ.w - mu) * inv * lw.w + lb.w;                            \
        op.x = xn.x + mx.x * av.x; op.y = xn.y + mx.y * av.y;              \
        op.z = xn.z + mx.z * av.z; op.w = xn.w + mx.w * av.w;              \
        acc += dotp4(PA, op);                                              \
        if ((QI >> 1) == rh) {                                             \
            const float4 mr4 = MRv[lane + QI * 64];                        \
            op.x = xn.x + mr4.x * av.x; op.y = xn.y + mr4.y * av.y;        \
            op.z = xn.z + mr4.z * av.z; op.w = xn.w + mr4.w * av.w;        \
            accR += dotp4(((QI & 1) ? rA1 : rA0), op);                     \
        }                                                                  \
    }

#define PHASE_C_Q(SQ, PC1, PC2, QI)                                        \
    {                                                                      \
        const float4 lw = LW2[lane + QI * 64];                             \
        const float4 lb = LB2[lane + QI * 64];                             \
        const float4 sd4 = SDv[lane + QI * 64];                            \
        const float4 mf = MKFv[lane + QI * 64];                            \
        float4 x2, op;                                                     \
        x2.x = (SQ.x - mu) * inv * lw.x + lb.x;                            \
        x2.y = (SQ.y - mu) * inv * lw.y + lb.y;                            \
        x2.z = (SQ.z - mu) * inv * lw.z + lb.z;                            \
        x2.w = (SQ.w - mu) * inv * lw.w + lb.w;                            \
        op.x = x2.x + mf.x * sd4.x; op.y = x2.y + mf.y * sd4.y;            \
        op.z = x2.z + mf.z * sd4.z; op.w = x2.w + mf.w * sd4.w;            \
        accF1 += dotp4(PC1, op);                                           \
        accF2 += dotp4(PC2, op);                                           \
        if ((QI >> 1) == rh) {                                             \
            const float4 mr4 = MRFv[lane + QI * 64];                       \
            op.x = x2.x + mr4.x * sd4.x; op.y = x2.y + mr4.y * sd4.y;      \
            op.z = x2.z + mr4.z * sd4.z; op.w = x2.w + mr4.w * sd4.w;      \
            accRF += dotp4(((QI & 1) ? rC1 : rC0), op);                    \
        }                                                                  \
    }

__global__ __launch_bounds__(NT, 2) void rwkv_persistent(
    const float* __restrict__ x_in, const float* __restrict__ state,
    const float* __restrict__ ln1w, const float* __restrict__ ln1b,
    const float* __restrict__ ln2w, const float* __restrict__ ln2b,
    const float* __restrict__ td, const float* __restrict__ tf,
    const float* __restrict__ key, const float* __restrict__ ow,
    const float* __restrict__ mixk, const float* __restrict__ mixv,
    const float* __restrict__ mixr, const float* __restrict__ mixkf,
    const float* __restrict__ mixrf, const float* __restrict__ kffn,
    const float* __restrict__ rffn, const float* __restrict__ vffn,
    float* __restrict__ out, float* __restrict__ ws, unsigned* __restrict__ grp,
    unsigned* __restrict__ rel) {
    __shared__ float red[32];
    // red[0..15]: dot partials; red[16..23]: half-dot partials;
    // red[24..27]: x[4b..4b+4) handoff (A->B); red[28..31]: sx handoff (C->D)

    float* kbuf = ws;          // [1024] exp(k)         (coherent)
    float* vbuf = ws + 1024;   // [1024] v
    float* rbuf = ws + 2048;   // [1024] rhat=exp(r)+1  (combined in A tail)
    float* sxbuf = ws + 3072;  // [1024] sx             (combined in B tail)
    float* kfbuf = ws + 4096;  // [4096] relu^2(kf)
    float* xnext = ws + 8192;  // [1024] next-layer x   (combined in D tail)

    float* sa_out = out + EDIM;
    float* sb_out = sa_out + LNUM * EDIM;
    float* sc_out = sb_out + LNUM * EDIM;
    float* sd_out = sc_out + LNUM * EDIM;

    const float* stB = state + 1 * LNUM * EDIM;
    const float* stC = state + 2 * LNUM * EDIM;

    const int t = threadIdx.x;
    const int b = blockIdx.x;
    const int w = t >> 6;
    const int lane = t & 63;
    const int gw = (b << 3) + w;           // 0..2047
    const int mat = gw >> 10;              // 0 -> k row, 1 -> v row
    const int rrow = (b << 2) + (w >> 1);  // r / ow / rfw row; half rh
    const int rh = w & 1;
    const int drow = (b << 2) + (w >> 2);  // vfw rows; chunk dch
    const int dch = w & 3;
    const int eb = b << 2;   // block's owned 4-element slice base
    const int e0 = lane << 2;  // lane's first element within a 256-span
    unsigned bi = 0;

    float4 pA0, pA1, pA2, pA3, rA0, rA1;
    float4 pB0, pB1;
    float4 pC10, pC11, pC12, pC13, pC20, pC21, pC22, pC23, rC0, rC1;
    float4 pD0, pD1, pD2, pD3, pD4, pD5, pD6, pD7;

    // Prologue: layer-0 phase-A weights (normal loads).
    {
        const float4* qA = (const float4*)(key + ((size_t)gw << 10));
        pA0 = qA[lane]; pA1 = qA[lane + 64]; pA2 = qA[lane + 128]; pA3 = qA[lane + 192];
        const float4* qR =
            (const float4*)(key + ((size_t)(2048 + rrow) << 10) + (rh << 9));
        rA0 = qR[lane]; rA1 = qR[lane + 64];
    }

    for (int l = 0; l < LNUM; ++l) {
        const float* owl = ow + (size_t)l * EDIM * EDIM;
        const float* kfl = kffn + (size_t)l * FDIM * EDIM;
        const float* rfl = rffn + (size_t)l * EDIM * EDIM;
        const float* vfl = vffn + (size_t)l * EDIM * FDIM;
        const int le = l * EDIM;
        float gt = 0.0f;  // sigmoid gate, lives C-tail -> D-tail in register

        // ========== Phase A: per-wave LN1 + k/v/r dots, register-direct ==========
        {
            float4 xq0, xq1, xq2, xq3;
            if (l == 0) {
                const float4* xp = (const float4*)x_in;
                xq0 = xp[lane]; xq1 = xp[lane + 64];
                xq2 = xp[lane + 128]; xq3 = xp[lane + 192];
            } else {
                xq0 = cload4(xnext + e0);
                xq1 = cload4(xnext + 256 + e0);
                xq2 = cload4(xnext + 512 + e0);
                xq3 = cload4(xnext + 768 + e0);
            }
            // full-vector stats from one wave (lanes cover all 1024 elements)
            const float s = (xq0.x + xq0.y + xq0.z + xq0.w) +
                            (xq1.x + xq1.y + xq1.z + xq1.w) +
                            (xq2.x + xq2.y + xq2.z + xq2.w) +
                            (xq3.x + xq3.y + xq3.z + xq3.w);
            const float s2 = dotp4(xq0, xq0) + dotp4(xq1, xq1) +
                             dotp4(xq2, xq2) + dotp4(xq3, xq3);
            const float2 ss = wave_sum2(s, s2);
            const float mu = ss.x * (1.0f / 1024.0f);
            const float inv = rsqrtf(ss.y * (1.0f / 1024.0f) - mu * mu + 1e-5f);

            const float4* LW1 = (const float4*)(ln1w + le);
            const float4* LB1 = (const float4*)(ln1b + le);
            const float4* SAv = (const float4*)(state + le);
            const float4* MXv = (const float4*)((mat ? mixv : mixk) + le);
            const float4* MRv = (const float4*)(mixr + le);
            float acc = 0.0f, accR = 0.0f;
            PHASE_A_Q(xq0, pA0, 0)
            PHASE_A_Q(xq1, pA1, 1)
            PHASE_A_Q(xq2, pA2, 2)
            PHASE_A_Q(xq3, pA3, 3)
            const float2 dv = wave_sum2(acc, accR);
            if (lane == 0) {
                if (mat == 0) cstore1(kbuf + gw, expf(dv.x));
                else          cstore1(vbuf + gw - 1024, dv.x);
                red[16 + w] = dv.y;
            }
            // sa output + x handoff for B tail (wave 0, one lane)
            if (w == 0) {
                const int q = b >> 6;  // uniform per block
                const float4 xs = q == 0 ? xq0 : q == 1 ? xq1 : q == 2 ? xq2 : xq3;
                if (lane == (b & 63)) {
                    const float4 lw = *(const float4*)(ln1w + le + eb);
                    const float4 lb = *(const float4*)(ln1b + le + eb);
                    float4 xn;
                    xn.x = (xs.x - mu) * inv * lw.x + lb.x;
                    xn.y = (xs.y - mu) * inv * lw.y + lb.y;
                    xn.z = (xs.z - mu) * inv * lw.z + lb.z;
                    xn.w = (xs.w - mu) * inv * lw.w + lb.w;
                    *(float4*)(sa_out + le + eb) = xn;
                    red[24] = xs.x; red[25] = xs.y; red[26] = xs.z; red[27] = xs.w;
                }
            }
            lbar();
            if (t < 4)
                cstore1(rbuf + eb + t, expf(red[16 + 2 * t] + red[17 + 2 * t]) + 1.0f);
        }
        FENCE();
        {   // window A->B: pB (ow half-row) + pC1 (kfw row gw) = 6 loads
            const float4* qB = (const float4*)(owl + ((size_t)rrow << 10) + (rh << 9));
            pB0 = qB[lane]; pB1 = qB[lane + 64];
            const float4* q1 = (const float4*)(kfl + ((size_t)gw << 10));
            pC10 = q1[lane]; pC11 = q1[lane + 64]; pC12 = q1[lane + 128]; pC13 = q1[lane + 192];
        }
        gbar<6>(grp, rel, bi);

        // ========== Phase B: WKV elementwise (register) + ow half-dot ==========
        {
            float kj = 0.0f, vj = 0.0f;
            if (t < 4) { kj = cload1(kbuf + eb + t); vj = cload1(vbuf + eb + t); }
            const int gp0 = (rh << 9) + e0;
            const int gp1 = gp0 + 256;
            const float4 k0 = cload4(kbuf + gp0), k1 = cload4(kbuf + gp1);
            const float4 v0 = cload4(vbuf + gp0), v1 = cload4(vbuf + gp1);
            const float4 r0 = cload4(rbuf + gp0), r1 = cload4(rbuf + gp1);
            const float4 tf0 = *(const float4*)(tf + le + gp0);
            const float4 tf1 = *(const float4*)(tf + le + gp1);
            const float4 sb0 = *(const float4*)(stB + le + gp0);
            const float4 sb1 = *(const float4*)(stB + le + gp1);
            const float4 sc0 = *(const float4*)(stC + le + gp0);
            const float4 sc1 = *(const float4*)(stC + le + gp1);
            float4 g0, g1;
            g0.x = (sb0.x + tf0.x * k0.x * v0.x) / (sc0.x * r0.x + tf0.x * k0.x * r0.x);
            g0.y = (sb0.y + tf0.y * k0.y * v0.y) / (sc0.y * r0.y + tf0.y * k0.y * r0.y);
            g0.z = (sb0.z + tf0.z * k0.z * v0.z) / (sc0.z * r0.z + tf0.z * k0.z * r0.z);
            g0.w = (sb0.w + tf0.w * k0.w * v0.w) / (sc0.w * r0.w + tf0.w * k0.w * r0.w);
            g1.x = (sb1.x + tf1.x * k1.x * v1.x) / (sc1.x * r1.x + tf1.x * k1.x * r1.x);
            g1.y = (sb1.y + tf1.y * k1.y * v1.y) / (sc1.y * r1.y + tf1.y * k1.y * r1.y);
            g1.z = (sb1.z + tf1.z * k1.z * v1.z) / (sc1.z * r1.z + tf1.z * k1.z * r1.z);
            g1.w = (sb1.w + tf1.w * k1.w * v1.w) / (sc1.w * r1.w + tf1.w * k1.w * r1.w);
            const float pd = wave_sum(dotp4(pB0, g0) + dotp4(pB1, g1));
            if (lane == 0) red[w] = pd;
            if (t < 4) {  // state outputs for own slice
                const int j = le + eb + t;
                const float tdj = td[j];
                sb_out[j] = stB[j] * tdj + kj * vj;
                sc_out[j] = stC[j] * tdj + kj;
            }
            lbar();
            if (t < 4)
                cstore1(sxbuf + eb + t, red[24 + t] + red[2 * t] + red[2 * t + 1]);
        }
        FENCE();
        {   // window B->C: pC2 (kfw row gw+2048) + rC (rfw half-row) = 6 loads
            const float4* q2 = (const float4*)(kfl + ((size_t)(gw + 2048) << 10));
            pC20 = q2[lane]; pC21 = q2[lane + 64]; pC22 = q2[lane + 128]; pC23 = q2[lane + 192];
            const float4* qR = (const float4*)(rfl + ((size_t)rrow << 10) + (rh << 9));
            rC0 = qR[lane]; rC1 = qR[lane + 64];
        }
        gbar<6>(grp, rel, bi);

        // ========== Phase C: per-wave LN2 + kf/rf dots, register-direct ==========
        {
            const float4 sq0 = cload4(sxbuf + e0);
            const float4 sq1 = cload4(sxbuf + 256 + e0);
            const float4 sq2 = cload4(sxbuf + 512 + e0);
            const float4 sq3 = cload4(sxbuf + 768 + e0);
            const float s = (sq0.x + sq0.y + sq0.z + sq0.w) +
                            (sq1.x + sq1.y + sq1.z + sq1.w) +
                            (sq2.x + sq2.y + sq2.z + sq2.w) +
                            (sq3.x + sq3.y + sq3.z + sq3.w);
            const float s2 = dotp4(sq0, sq0) + dotp4(sq1, sq1) +
                             dotp4(sq2, sq2) + dotp4(sq3, sq3);
            const float2 ss = wave_sum2(s, s2);
            const float mu = ss.x * (1.0f / 1024.0f);
            const float inv = rsqrtf(ss.y * (1.0f / 1024.0f) - mu * mu + 1e-5f);

            const float4* LW2 = (const float4*)(ln2w + le);
            const float4* LB2 = (const float4*)(ln2b + le);
            const float4* SDv = (const float4*)(state + 3 * LNUM * EDIM + le);
            const float4* MKFv = (const float4*)(mixkf + le);
            const float4* MRFv = (const float4*)(mixrf + le);
            float accF1 = 0.0f, accF2 = 0.0f, accRF = 0.0f;
            PHASE_C_Q(sq0, pC10, pC20, 0)
            PHASE_C_Q(sq1, pC11, pC21, 1)
            PHASE_C_Q(sq2, pC12, pC22, 2)
            PHASE_C_Q(sq3, pC13, pC23, 3)
            const float2 df = wave_sum2(accF1, accF2);
            const float dr = wave_sum(accRF);
            if (lane == 0) {
                float r1 = fmaxf(df.x, 0.0f);
                float r2 = fmaxf(df.y, 0.0f);
                cstore1(kfbuf + gw, r1 * r1);
                cstore1(kfbuf + gw + 2048, r2 * r2);
                red[16 + w] = dr;
            }
            // sd output + sx handoff for D tail (wave 0, one lane)
            if (w == 0) {
                const int q = b >> 6;
                const float4 xs = q == 0 ? sq0 : q == 1 ? sq1 : q == 2 ? sq2 : sq3;
                if (lane == (b & 63)) {
                    const float4 lw = *(const float4*)(ln2w + le + eb);
                    const float4 lb = *(const float4*)(ln2b + le + eb);
                    float4 x2;
                    x2.x = (xs.x - mu) * inv * lw.x + lb.x;
                    x2.y = (xs.y - mu) * inv * lw.y + lb.y;
                    x2.z = (xs.z - mu) * inv * lw.z + lb.z;
                    x2.w = (xs.w - mu) * inv * lw.w + lb.w;
                    *(float4*)(sd_out + le + eb) = x2;
                    red[28] = xs.x; red[29] = xs.y; red[30] = xs.z; red[31] = xs.w;
                }
            }
            lbar();
            if (t < 4)
                gt = 1.0f / (1.0f + expf(red[16 + 2 * t] + red[17 + 2 * t]));
        }
        FENCE();
        {   // window C->D: both vfw chunk-units = 8 loads
            const float4* q1 = (const float4*)(vfl + ((size_t)drow << 12) + (dch << 10));
            pD0 = q1[lane]; pD1 = q1[lane + 64]; pD2 = q1[lane + 128]; pD3 = q1[lane + 192];
            const float4* q2 =
                (const float4*)(vfl + ((size_t)(drow + 2) << 12) + (dch << 10));
            pD4 = q2[lane]; pD5 = q2[lane + 64]; pD6 = q2[lane + 128]; pD7 = q2[lane + 192];
        }
        gbar<8>(grp, rel, bi);

        // ========== Phase D: vfw dots, register-direct; combine + gate in tail ==========
        {
            const int kp = dch << 10;
            const float4 o0 = cload4(kfbuf + kp + e0);
            const float4 o1 = cload4(kfbuf + kp + 256 + e0);
            const float4 o2 = cload4(kfbuf + kp + 512 + e0);
            const float4 o3 = cload4(kfbuf + kp + 768 + e0);
            const float2 dd = wave_sum2(
                dotp4(pD0, o0) + dotp4(pD1, o1) + dotp4(pD2, o2) + dotp4(pD3, o3),
                dotp4(pD4, o0) + dotp4(pD5, o1) + dotp4(pD6, o2) + dotp4(pD7, o3));
            if (lane == 0) { red[w] = dd.x; red[8 + w] = dd.y; }
            lbar();
            if (t < 4) {
                const float ffn =
                    red[4 * t] + red[4 * t + 1] + red[4 * t + 2] + red[4 * t + 3];
                const float val = red[28 + t] + ffn * gt;
                if (l == LNUM - 1) out[eb + t] = val;  // final output
                else cstore1(xnext + eb + t, val);
            }
        }
        if (l < LNUM - 1) {
            FENCE();
            {   // window D->A': next layer's phase-A weights = 6 loads
                const float* keyn = key + (size_t)(l + 1) * 3 * EDIM * EDIM;
                const float4* qA = (const float4*)(keyn + ((size_t)gw << 10));
                pA0 = qA[lane]; pA1 = qA[lane + 64]; pA2 = qA[lane + 128]; pA3 = qA[lane + 192];
                const float4* qR =
                    (const float4*)(keyn + ((size_t)(2048 + rrow) << 10) + (rh << 9));
                rA0 = qR[lane]; rA1 = qR[lane + 64];
            }
            gbar<6>(grp, rel, bi);
        }
    }
}

extern "C" void kernel_launch(void* const* d_in, const int* in_sizes, int n_in,
                              void* d_out, int out_size, void* d_ws, size_t ws_size,
                              hipStream_t stream) {
    const float* x_in = (const float*)d_in[0];
    const float* state = (const float*)d_in[1];
    const float* ln1w = (const float*)d_in[2];
    const float* ln1b = (const float*)d_in[3];
    const float* ln2w = (const float*)d_in[4];
    const float* ln2b = (const float*)d_in[5];
    const float* td = (const float*)d_in[6];
    const float* tf = (const float*)d_in[7];
    const float* key = (const float*)d_in[8];
    const float* ow = (const float*)d_in[9];
    const float* mixk = (const float*)d_in[10];
    const float* mixv = (const float*)d_in[11];
    const float* mixr = (const float*)d_in[12];
    const float* mixkf = (const float*)d_in[13];
    const float* mixrf = (const float*)d_in[14];
    const float* kffn = (const float*)d_in[15];
    const float* rffn = (const float*)d_in[16];
    const float* vffn = (const float*)d_in[17];

    float* out = (float*)d_out;
    float* ws = (float*)d_ws;

    // Vector region: 9216 floats = 36 KB. Barrier state at 48 KB:
    // 8 arrival lines (64 B each) + 8 release lines.
    unsigned* bar = (unsigned*)((char*)d_ws + 48 * 1024);
    unsigned* grp = bar;         // grp[g<<4], g=0..7
    unsigned* rel = bar + 256;   // rel[g<<4], g=0..7 (+1 KB)

    hipMemsetAsync(bar, 0, 2048, stream);  // deterministic per replay
    rwkv_persistent<<<NB, NT, 0, stream>>>(x_in, state, ln1w, ln1b, ln2w, ln2b, td, tf,
                                           key, ow, mixk, mixv, mixr, mixkf, mixrf,
                                           kffn, rffn, vffn, out, ws, grp, rel);
}